// Round 8
// baseline (131.495 us; speedup 1.0000x reference)
//
#include <hip/hip_runtime.h>
#include <cmath>

// Problem constants (from reference): N=2, Lq=Lk=1024, H=8, d=64, P=1, D=512
#define NB    2
#define LSEQ  1024
#define NH    8
#define HD    64
#define DD    512    // NH*HD
#define FDIM  128    // 2*HD  (cos|sin features)
#define EV    65     // HD + 1 (values + denominator unit column)
#define CHUNK 64
#define NC    16     // LSEQ / CHUNK
#define NBH   16     // NB*NH

typedef short short8 __attribute__((ext_vector_type(8)));   // 8 bf16 (4 VGPRs)
typedef float floatx4 __attribute__((ext_vector_type(4)));  // MFMA C/D frag
typedef unsigned short ushort;

__device__ __forceinline__ float softplusf(float x) {
  return fmaxf(x, 0.0f) + log1pf(expf(-fabsf(x)));
}

__device__ __forceinline__ ushort f2bf(float f) {
  unsigned u = __float_as_uint(f);
  u += 0x7fffu + ((u >> 16) & 1u);
  return (ushort)(u >> 16);
}

__device__ __forceinline__ short8 cvt8(float4 a, float4 b) {
  short8 r;
  r[0] = (short)f2bf(a.x); r[1] = (short)f2bf(a.y);
  r[2] = (short)f2bf(a.z); r[3] = (short)f2bf(a.w);
  r[4] = (short)f2bf(b.x); r[5] = (short)f2bf(b.y);
  r[6] = (short)f2bf(b.z); r[7] = (short)f2bf(b.w);
  return r;
}

// ---------------------------------------------------------------------------
// K1 v3: ALL projections, bf16 MFMA, K-slice 64, register double-buffering.
// Outputs now bf16: Qf/Kf as [bh][l][f] (MFMA A/B-frag row layout),
// V as V^T [bh][e][l] with ones-row at e=64 (so chunk_sums/chunk_out read
// B-frags straight from global). Blocks 0..255: q; 256..767: k/v.
// ---------------------------------------------------------------------------
__global__ __launch_bounds__(256) void k_proj(
    const float* __restrict__ Xq, const float* __restrict__ Xkv,
    const float* __restrict__ Wq, const float* __restrict__ Wk,
    const float* __restrict__ Wv, const float* __restrict__ pw,
    const float* __restrict__ pb, const float* __restrict__ pc,
    ushort* __restrict__ Qfb, ushort* __restrict__ Kfb,
    ushort* __restrict__ VTb)
{
  __shared__ short Al[64][72];   // [m][k] bf16 (9216 B)
  __shared__ short Bl[64][72];   // [e][k] bf16 (9216 B)
  const int b = blockIdx.x;
  int m0, e0, pmode;             // 0 = q, 1 = k, 2 = v
  const float *X, *W;
  if (b < 256) {
    m0 = (b >> 3) << 6; e0 = (b & 7) << 6;
    X = Xq; W = Wq + (size_t)e0 * DD; pmode = 0;
  } else {
    const int bb = b - 256;
    m0 = (bb >> 4) << 6;
    const int nt = bb & 15;
    e0 = (nt & 7) << 6;
    X = Xkv;
    if (nt < 8) { W = Wk + (size_t)e0 * DD; pmode = 1; }
    else        { W = Wv + (size_t)e0 * DD; pmode = 2; }
  }
  const int tid  = threadIdx.x;
  const int r    = tid >> 2;               // staging row 0..63
  const int ko   = (tid & 3) << 4;         // 0,16,32,48 shorts
  const int wave = tid >> 6, lane = tid & 63;
  const int quad = lane >> 4, lm = lane & 15;
  const float* Ag = X + (size_t)(m0 + r) * DD + ko;
  const float* Bg = W + (size_t)r * DD + ko;
  float4 a[4], bb4[4];
#pragma unroll
  for (int u = 0; u < 4; ++u) {
    a[u]   = *(const float4*)(Ag + (u << 2));
    bb4[u] = *(const float4*)(Bg + (u << 2));
  }
  floatx4 acc[4] = {};
  for (int k0 = 0; k0 < DD; k0 += 64) {
    __syncthreads();
    *(short8*)&Al[r][ko]     = cvt8(a[0], a[1]);
    *(short8*)&Al[r][ko + 8] = cvt8(a[2], a[3]);
    *(short8*)&Bl[r][ko]     = cvt8(bb4[0], bb4[1]);
    *(short8*)&Bl[r][ko + 8] = cvt8(bb4[2], bb4[3]);
    __syncthreads();
    if (k0 + 64 < DD) {
#pragma unroll
      for (int u = 0; u < 4; ++u) {
        a[u]   = *(const float4*)(Ag + k0 + 64 + (u << 2));
        bb4[u] = *(const float4*)(Bg + k0 + 64 + (u << 2));
      }
    }
#pragma unroll
    for (int ks = 0; ks < 2; ++ks) {
      const short8 af = *(const short8*)&Al[(wave << 4) + lm][(quad << 3) + (ks << 5)];
#pragma unroll
      for (int t = 0; t < 4; ++t) {
        const short8 bf = *(const short8*)&Bl[(t << 4) + lm][(quad << 3) + (ks << 5)];
        acc[t] = __builtin_amdgcn_mfma_f32_16x16x32_bf16(af, bf, acc[t], 0, 0, 0);
      }
    }
  }
  if (pmode == 2) {
    const int h  = e0 >> 6;
    const int n  = m0 >> 10;
    const int l0 = m0 & 1023;
    const int bh = n * NH + h;
#pragma unroll
    for (int t = 0; t < 4; ++t) {
      const int jj = (t << 4) + lm;        // e within head, 0..63
#pragma unroll
      for (int rg = 0; rg < 4; ++rg) {
        const int l = l0 + (wave << 4) + (quad << 2) + rg;
        VTb[((size_t)bh * 80 + jj) * LSEQ + l] = f2bf(acc[t][rg]);
      }
    }
    // ones-row at e=64 for this (bh, l-range)
    if (tid < 64) VTb[((size_t)bh * 80 + 64) * LSEQ + l0 + tid] = 0x3F80u;
  } else {
    ushort* base = (pmode == 0) ? Qfb : Kfb;
#pragma unroll
    for (int t = 0; t < 4; ++t) {
      const int e = e0 + (t << 4) + lm;
      const int h = e >> 6, jj = e & 63;
      const float pwv = pw[e];
      const float pbv = (pmode == 0) ? pb[e] : 0.0f;
      const float pcv = (pmode == 0) ? pc[e] : 1.0f;
#pragma unroll
      for (int rg = 0; rg < 4; ++rg) {
        const int m = m0 + (wave << 4) + (quad << 2) + rg;
        const int n = m >> 10, l = m & 1023;
        const float v = softplusf(acc[t][rg]) * pcv;
        const float ang = fmaf((float)l, pwv, pbv);
        ushort* dst = &base[((size_t)(n * NH + h) * LSEQ + l) * FDIM + jj];
        dst[0]  = f2bf(v * __cosf(ang));
        dst[64] = f2bf(v * __sinf(ang));
      }
    }
  }
}

// ---------------------------------------------------------------------------
// K2 v3: per-chunk state sums on bf16 MFMA. A = K^T (LDS transpose from
// bf16 Kf), B = V^T straight from global (already transposed, ones at e=64).
// Grid 512: blk = bh*32 + c*2 + fh. Writes S [f][e] fp32.
// ---------------------------------------------------------------------------
__global__ __launch_bounds__(256) void k_chunk_sums(
    const ushort* __restrict__ Kfb, const ushort* __restrict__ VTb,
    float* __restrict__ S)
{
  const int blk = blockIdx.x;
  const int bh  = blk >> 5;
  const int c   = (blk >> 1) & (NC - 1);
  const int fh  = blk & 1;
  const int f0  = fh << 6;
  const int t0  = c * CHUNK;
  const int tid  = threadIdx.x;
  const int wave = tid >> 6, lane = tid & 63;
  const int quad = lane >> 4, lm = lane & 15;

  __shared__ short KT[64][72];   // [f-f0][t] bf16, 9216 B

  // stage K^T for this f-half (short8 reads, 2B LDS scatter: 2-way max)
  for (int i = tid; i < 64 * 8; i += 256) {
    const int t = i & 63, f8 = (i >> 6) << 3;
    const short8 k8 = *(const short8*)&Kfb[((size_t)bh * LSEQ + t0 + t) * FDIM + f0 + f8];
#pragma unroll
    for (int u = 0; u < 8; ++u) KT[f8 + u][t] = k8[u];
  }
  __syncthreads();

  short8 aK[2];
#pragma unroll
  for (int ks = 0; ks < 2; ++ks)
    aK[ks] = *(const short8*)&KT[(wave << 4) + lm][(quad << 3) + (ks << 5)];
  floatx4 acc[5] = {};
#pragma unroll
  for (int nt = 0; nt < 5; ++nt)
#pragma unroll
    for (int ks = 0; ks < 2; ++ks) {
      const short8 bf = *(const short8*)
          &VTb[((size_t)bh * 80 + (nt << 4) + lm) * LSEQ + t0 + (quad << 3) + (ks << 5)];
      acc[nt] = __builtin_amdgcn_mfma_f32_16x16x32_bf16(aK[ks], bf, acc[nt], 0, 0, 0);
    }

  float* Sb = &S[(size_t)(bh * NC + c) * FDIM * EV];
#pragma unroll
  for (int nt = 0; nt < 4; ++nt)
#pragma unroll
    for (int rg = 0; rg < 4; ++rg) {
      const int f = f0 + (wave << 4) + (quad << 2) + rg;
      Sb[f * EV + (nt << 4) + lm] = acc[nt][rg];
    }
  if (lm == 0) {
#pragma unroll
    for (int rg = 0; rg < 4; ++rg) {
      const int f = f0 + (wave << 4) + (quad << 2) + rg;
      Sb[f * EV + 64] = acc[4][rg];
    }
  }
}

// ---------------------------------------------------------------------------
// K3 v3: exclusive prefix scan over NC chunk states; emits the prefix
// directly as bf16 B-frag layout PTg [bh*NC+c][80][128] ([e][f], rows 65..79
// left as poison -> only feed discarded D columns). Reads S fp32 (scattered
// but independent loads), writes coalesced bf16.
// ---------------------------------------------------------------------------
__global__ __launch_bounds__(256) void k_scan(
    const float* __restrict__ S, ushort* __restrict__ PTb)
{
  const int bh = blockIdx.x / 13;
  const int eg = blockIdx.x % 13;          // 13 groups of 5 e-values (65 total)
  const size_t cs = (size_t)FDIM * EV;
  for (int i = threadIdx.x; i < 5 * FDIM; i += 256) {
    const int e = eg * 5 + (i >> 7);
    const int f = i & 127;
    const float* p = S + (size_t)(bh * NC) * cs + f * EV + e;
    float v[NC];
#pragma unroll
    for (int c = 0; c < NC; ++c) v[c] = p[c * cs];
    float s = 0.0f;
#pragma unroll
    for (int c = 0; c < NC; ++c) {
      PTb[((size_t)(bh * NC + c) * 80 + e) * 128 + f] = f2bf(s);
      s += v[c];
    }
  }
}

// ---------------------------------------------------------------------------
// K4 v5: per-chunk output, zero barriers, zero staging. All MFMA operands
// are contiguous 16B global loads (bf16 tensors are stored in frag layout);
// only the score matrix round-trips through LDS (same-wave write->read).
// ---------------------------------------------------------------------------
__global__ __launch_bounds__(256) void k_chunk_out(
    const ushort* __restrict__ Qfb, const ushort* __restrict__ Kfb,
    const ushort* __restrict__ VTb, const ushort* __restrict__ PTb,
    float* __restrict__ Out)
{
  const int c  = blockIdx.x & (NC - 1);
  const int bh = blockIdx.x >> 4;
  const int n  = bh >> 3, h = bh & 7;
  const int t0 = c * CHUNK;
  const int tid  = threadIdx.x;
  const int wave = tid >> 6, lane = tid & 63;
  const int quad = lane >> 4, lm = lane & 15;

  __shared__ short ScL[64][72];    // [m][t] bf16, 9216 B
  __shared__ float DenL[64];       //   256 B

  const size_t qkBase = (size_t)bh * LSEQ + t0;
  const int ks_off = quad << 3;

  // A frags: this wave's 16 Q rows
  short8 aQ[4];
#pragma unroll
  for (int ks = 0; ks < 4; ++ks)
    aQ[ks] = *(const short8*)&Qfb[(qkBase + (wave << 4) + lm) * FDIM + ks_off + (ks << 5)];

  // phase 1: scores Sc = Q @ K^T (B rows = K rows, contiguous in f)
  floatx4 accS[4] = {};
#pragma unroll
  for (int nt = 0; nt < 4; ++nt)
#pragma unroll
    for (int ks = 0; ks < 4; ++ks) {
      const short8 b = *(const short8*)&Kfb[(qkBase + (nt << 4) + lm) * FDIM + ks_off + (ks << 5)];
      accS[nt] = __builtin_amdgcn_mfma_f32_16x16x32_bf16(aQ[ks], b, accS[nt], 0, 0, 0);
    }
#pragma unroll
  for (int nt = 0; nt < 4; ++nt)
#pragma unroll
    for (int rg = 0; rg < 4; ++rg) {
      const int m = (wave << 4) + (quad << 2) + rg;
      const int t = (nt << 4) + lm;
      ScL[m][t] = (short)((t <= m) ? f2bf(accS[nt][rg]) : 0);
    }

  // phase 2: num = Q @ P (+den col at row 64); PT already bf16 [e][f]
  const ushort* Pg = &PTb[(size_t)(bh * NC + c) * 80 * 128];
  floatx4 accN[5] = {};
#pragma unroll
  for (int nt = 0; nt < 5; ++nt)
#pragma unroll
    for (int ks = 0; ks < 4; ++ks) {
      const short8 b = *(const short8*)&Pg[(size_t)((nt << 4) + lm) * 128 + ks_off + (ks << 5)];
      accN[nt] = __builtin_amdgcn_mfma_f32_16x16x32_bf16(aQ[ks], b, accN[nt], 0, 0, 0);
    }

  // phase 3: PV = Sc @ Vext (+rowsum col); same-wave ScL access, no barrier
  short8 aS[2];
#pragma unroll
  for (int ks = 0; ks < 2; ++ks)
    aS[ks] = *(const short8*)&ScL[(wave << 4) + lm][ks_off + (ks << 5)];
  floatx4 accV[5] = {};
#pragma unroll
  for (int nt = 0; nt < 5; ++nt)
#pragma unroll
    for (int ks = 0; ks < 2; ++ks) {
      const short8 b = *(const short8*)
          &VTb[((size_t)bh * 80 + (nt << 4) + lm) * LSEQ + t0 + ks_off + (ks << 5)];
      accV[nt] = __builtin_amdgcn_mfma_f32_16x16x32_bf16(aS[ks], b, accV[nt], 0, 0, 0);
    }

  if (lm == 0) {
#pragma unroll
    for (int rg = 0; rg < 4; ++rg)
      DenL[(wave << 4) + (quad << 2) + rg] = accN[4][rg] + accV[4][rg];
  }

#pragma unroll
  for (int rg = 0; rg < 4; ++rg) {
    const int m = (wave << 4) + (quad << 2) + rg;
    const float rden = 1.0f / DenL[m];
    const int l = t0 + m;
#pragma unroll
    for (int nt = 0; nt < 4; ++nt) {
      const float val = (accN[nt][rg] + accV[nt][rg]) * rden;
      Out[((size_t)(n * LSEQ + l)) * DD + h * HD + (nt << 4) + lm] = val;
    }
  }
}

// ---------------------------------------------------------------------------
extern "C" void kernel_launch(void* const* d_in, const int* in_sizes, int n_in,
                              void* d_out, int out_size, void* d_ws, size_t ws_size,
                              hipStream_t stream) {
  (void)in_sizes; (void)n_in; (void)out_size; (void)ws_size;
  const float* query  = (const float*)d_in[0];
  const float* keyseq = (const float*)d_in[1];
  const float* Wq     = (const float*)d_in[2];
  const float* Wk     = (const float*)d_in[3];
  const float* Wv     = (const float*)d_in[4];
  const float* pc     = (const float*)d_in[5];  // position_coeffs (H,d)
  const float* pw     = (const float*)d_in[6];  // position_weight (H,d,1)
  const float* pb     = (const float*)d_in[7];  // position_bias (H,d)
  float* out = (float*)d_out;

  // workspace layout (bf16 intermediates in MFMA fragment layouts)
  ushort* Qfb = (ushort*)d_ws;                           // 16*1024*128 us = 4 MB
  ushort* Kfb = Qfb + (size_t)NBH * LSEQ * FDIM;         // 4 MB
  ushort* VTb = Kfb + (size_t)NBH * LSEQ * FDIM;         // 16*80*1024 us = 2.6 MB
  float*  S   = (float*)(VTb + (size_t)NBH * 80 * LSEQ); // 16*16*128*65 f = 8.5 MB
  ushort* PTb = (ushort*)(S + (size_t)NBH * NC * FDIM * EV); // 16*16*80*128 us = 5.2 MB

  k_proj      <<<768,          256, 0, stream>>>(query, keyseq, Wq, Wk, Wv, pw, pb, pc, Qfb, Kfb, VTb);
  k_chunk_sums<<<NBH * NC * 2, 256, 0, stream>>>(Kfb, VTb, S);
  k_scan      <<<NBH * 13,     256, 0, stream>>>(S, PTb);
  k_chunk_out <<<NBH * NC,     256, 0, stream>>>(Qfb, Kfb, VTb, PTb, out);
}

// Round 9
// 129.877 us; speedup vs baseline: 1.0125x; 1.0125x over previous
//
#include <hip/hip_runtime.h>
#include <cmath>

// Problem constants (from reference): N=2, Lq=Lk=1024, H=8, d=64, P=1, D=512
#define NB    2
#define LSEQ  1024
#define NH    8
#define HD    64
#define DD    512    // NH*HD
#define FDIM  128    // 2*HD  (cos|sin features)
#define EV    65     // HD + 1 (values + denominator unit column)
#define SEP   80     // padded e-extent of the stored chunk state
#define CHUNK 64
#define NC    16     // LSEQ / CHUNK
#define NBH   16     // NB*NH

typedef short short8 __attribute__((ext_vector_type(8)));   // 8 bf16 (4 VGPRs)
typedef float floatx4 __attribute__((ext_vector_type(4)));  // MFMA C/D frag

__device__ __forceinline__ float softplusf(float x) {
  return fmaxf(x, 0.0f) + log1pf(expf(-fabsf(x)));
}

__device__ __forceinline__ unsigned short f2bf(float f) {
  unsigned u = __float_as_uint(f);
  u += 0x7fffu + ((u >> 16) & 1u);
  return (unsigned short)(u >> 16);
}

__device__ __forceinline__ short8 cvt8(float4 a, float4 b) {
  short8 r;
  r[0] = (short)f2bf(a.x); r[1] = (short)f2bf(a.y);
  r[2] = (short)f2bf(a.z); r[3] = (short)f2bf(a.w);
  r[4] = (short)f2bf(b.x); r[5] = (short)f2bf(b.y);
  r[6] = (short)f2bf(b.z); r[7] = (short)f2bf(b.w);
  return r;
}

// ---------------------------------------------------------------------------
// K1: ALL projections, bf16 MFMA, K-slice 64, register double-buffering.
// (identical to round-7 version, the known-good 119.4 µs baseline)
// ---------------------------------------------------------------------------
__global__ __launch_bounds__(256) void k_proj(
    const float* __restrict__ Xq, const float* __restrict__ Xkv,
    const float* __restrict__ Wq, const float* __restrict__ Wk,
    const float* __restrict__ Wv, const float* __restrict__ pw,
    const float* __restrict__ pb, const float* __restrict__ pc,
    float* __restrict__ Qf, float* __restrict__ Kf, float* __restrict__ Vx)
{
  __shared__ short Al[64][72];   // [m][k] bf16 (9216 B)
  __shared__ short Bl[64][72];   // [e][k] bf16 (9216 B)
  const int b = blockIdx.x;
  int m0, e0, pmode;             // 0 = q, 1 = k, 2 = v
  const float *X, *W;
  if (b < 256) {
    m0 = (b >> 3) << 6; e0 = (b & 7) << 6;
    X = Xq; W = Wq + (size_t)e0 * DD; pmode = 0;
  } else {
    const int bb = b - 256;
    m0 = (bb >> 4) << 6;
    const int nt = bb & 15;
    e0 = (nt & 7) << 6;
    X = Xkv;
    if (nt < 8) { W = Wk + (size_t)e0 * DD; pmode = 1; }
    else        { W = Wv + (size_t)e0 * DD; pmode = 2; }
  }
  const int tid  = threadIdx.x;
  const int r    = tid >> 2;               // staging row 0..63
  const int ko   = (tid & 3) << 4;         // 0,16,32,48 shorts
  const int wave = tid >> 6, lane = tid & 63;
  const int quad = lane >> 4, lm = lane & 15;
  const float* Ag = X + (size_t)(m0 + r) * DD + ko;
  const float* Bg = W + (size_t)r * DD + ko;
  float4 a[4], bb4[4];
#pragma unroll
  for (int u = 0; u < 4; ++u) {
    a[u]   = *(const float4*)(Ag + (u << 2));
    bb4[u] = *(const float4*)(Bg + (u << 2));
  }
  floatx4 acc[4] = {};
  for (int k0 = 0; k0 < DD; k0 += 64) {
    __syncthreads();
    *(short8*)&Al[r][ko]     = cvt8(a[0], a[1]);
    *(short8*)&Al[r][ko + 8] = cvt8(a[2], a[3]);
    *(short8*)&Bl[r][ko]     = cvt8(bb4[0], bb4[1]);
    *(short8*)&Bl[r][ko + 8] = cvt8(bb4[2], bb4[3]);
    __syncthreads();
    if (k0 + 64 < DD) {
#pragma unroll
      for (int u = 0; u < 4; ++u) {
        a[u]   = *(const float4*)(Ag + k0 + 64 + (u << 2));
        bb4[u] = *(const float4*)(Bg + k0 + 64 + (u << 2));
      }
    }
#pragma unroll
    for (int ks = 0; ks < 2; ++ks) {
      const short8 af = *(const short8*)&Al[(wave << 4) + lm][(quad << 3) + (ks << 5)];
#pragma unroll
      for (int t = 0; t < 4; ++t) {
        const short8 bf = *(const short8*)&Bl[(t << 4) + lm][(quad << 3) + (ks << 5)];
        acc[t] = __builtin_amdgcn_mfma_f32_16x16x32_bf16(af, bf, acc[t], 0, 0, 0);
      }
    }
  }
#pragma unroll
  for (int t = 0; t < 4; ++t) {
    const int e = e0 + (t << 4) + lm;
    const int h = e >> 6, jj = e & 63;
    if (pmode == 2) {
#pragma unroll
      for (int rg = 0; rg < 4; ++rg) {
        const int m = m0 + (wave << 4) + (quad << 2) + rg;
        const int n = m >> 10, l = m & 1023;
        Vx[((size_t)(n * NH + h) * LSEQ + l) * HD + jj] = acc[t][rg];
      }
    } else {
      const float pwv = pw[e];
      const float pbv = (pmode == 0) ? pb[e] : 0.0f;
      const float pcv = (pmode == 0) ? pc[e] : 1.0f;
      float* base = (pmode == 0) ? Qf : Kf;
#pragma unroll
      for (int rg = 0; rg < 4; ++rg) {
        const int m = m0 + (wave << 4) + (quad << 2) + rg;
        const int n = m >> 10, l = m & 1023;
        const float v = softplusf(acc[t][rg]) * pcv;
        const float ang = fmaf((float)l, pwv, pbv);
        const float sn = __sinf(ang), cs = __cosf(ang);
        float* dst = &base[((size_t)(n * NH + h) * LSEQ + l) * FDIM + jj];
        dst[0]  = v * cs;
        dst[64] = v * sn;
      }
    }
  }
}

// ---------------------------------------------------------------------------
// K2: per-chunk state sums on bf16 MFMA, now stored TRANSPOSED + padded:
// S^T[bh*NC+c][e=0..79][f=0..127] fp32 (flat pow-2 strides; e rows 65..79
// never written -> poison only feeds discarded D columns downstream).
// Grid 512: blk = bh*32 + c*2 + fh (fh = f-half of 64 rows).
// ---------------------------------------------------------------------------
__global__ __launch_bounds__(256) void k_chunk_sums(
    const float* __restrict__ Kf, const float* __restrict__ Vx,
    float* __restrict__ S)
{
  const int blk = blockIdx.x;
  const int bh  = blk >> 5;
  const int c   = (blk >> 1) & (NC - 1);
  const int fh  = blk & 1;
  const int f0  = fh << 6;
  const int t0  = c * CHUNK;
  const int tid  = threadIdx.x;
  const int wave = tid >> 6, lane = tid & 63;
  const int quad = lane >> 4, lm = lane & 15;

  __shared__ short KT[64][72];   // [f-f0][t] bf16  9216 B
  __shared__ short VT[80][72];   // [e][t]    bf16 11520 B

  for (int i = tid; i < 64 * 16; i += 256) {
    const int t = i & 63, f4 = (i >> 6) << 2;
    const float4 k4 = *(const float4*)&Kf[((size_t)bh * LSEQ + t0 + t) * FDIM + f0 + f4];
    KT[f4 + 0][t] = (short)f2bf(k4.x);
    KT[f4 + 1][t] = (short)f2bf(k4.y);
    KT[f4 + 2][t] = (short)f2bf(k4.z);
    KT[f4 + 3][t] = (short)f2bf(k4.w);
  }
  for (int i = tid; i < 64 * 16; i += 256) {
    const int t = i & 63, e4 = (i >> 6) << 2;
    const float4 v4 = *(const float4*)&Vx[((size_t)bh * LSEQ + t0 + t) * HD + e4];
    VT[e4 + 0][t] = (short)f2bf(v4.x);
    VT[e4 + 1][t] = (short)f2bf(v4.y);
    VT[e4 + 2][t] = (short)f2bf(v4.z);
    VT[e4 + 3][t] = (short)f2bf(v4.w);
  }
  if (tid < CHUNK) VT[64][tid] = (short)0x3F80;   // bf16 1.0
  __syncthreads();

  short8 aK[2];
#pragma unroll
  for (int ks = 0; ks < 2; ++ks)
    aK[ks] = *(const short8*)&KT[(wave << 4) + lm][(quad << 3) + (ks << 5)];
  floatx4 acc[5] = {};
#pragma unroll
  for (int nt = 0; nt < 5; ++nt)
#pragma unroll
    for (int ks = 0; ks < 2; ++ks) {
      const short8 bf = *(const short8*)&VT[(nt << 4) + lm][(quad << 3) + (ks << 5)];
      acc[nt] = __builtin_amdgcn_mfma_f32_16x16x32_bf16(aK[ks], bf, acc[nt], 0, 0, 0);
    }

  // transposed store: S^T[e][f]
  float* Sb = &S[(size_t)(bh * NC + c) * SEP * FDIM];
#pragma unroll
  for (int nt = 0; nt < 4; ++nt)
#pragma unroll
    for (int rg = 0; rg < 4; ++rg) {
      const int f = f0 + (wave << 4) + (quad << 2) + rg;
      Sb[((nt << 4) + lm) * FDIM + f] = acc[nt][rg];
    }
  if (lm == 0) {
#pragma unroll
    for (int rg = 0; rg < 4; ++rg) {
      const int f = f0 + (wave << 4) + (quad << 2) + rg;
      Sb[64 * FDIM + f] = acc[4][rg];
    }
  }
}

// ---------------------------------------------------------------------------
// K3 (merged scan+output): per-chunk output, all three matmuls on bf16 MFMA.
// The exclusive prefix over previous chunk states is computed in-kernel
// during staging: flat coalesced reads of S^T, ILP-8 register tiles, fp32
// accumulate (same summation order as the old k_scan -> identical numerics),
// then f2bf into PT. One fewer kernel launch; S is read once.
// ---------------------------------------------------------------------------
__global__ __launch_bounds__(256) void k_chunk_out(
    const float* __restrict__ Qf, const float* __restrict__ Kf,
    const float* __restrict__ Vx, const float* __restrict__ S,
    float* __restrict__ Out)
{
  const int c  = blockIdx.x & (NC - 1);
  const int bh = blockIdx.x >> 4;
  const int n  = bh >> 3, h = bh & 7;
  const int t0 = c * CHUNK;
  const int tid  = threadIdx.x;
  const int wave = tid >> 6, lane = tid & 63;
  const int quad = lane >> 4, lm = lane & 15;

  __shared__ short QL[64][128];    // [t][f] bf16  16384 B
  __shared__ short KL[64][128];    // [t][f] bf16  16384 B
  __shared__ short ScL[64][72];    // [m][t] bf16   9216 B
  __shared__ short PT[80][136];    // [e][f] bf16  21760 B
  __shared__ short VT[80][72];     // [e][t] bf16  11520 B
  __shared__ float DenL[64];       //                256 B

  const float* Qg = &Qf[((size_t)bh * LSEQ + t0) * FDIM];
  const float* Kg = &Kf[((size_t)bh * LSEQ + t0) * FDIM];
  {
    const int f8 = (tid & 15) << 3;
#pragma unroll
    for (int rr = 0; rr < 64; rr += 16) {
      const int r = rr + (tid >> 4);
      const float4 a0 = *(const float4*)&Qg[r * FDIM + f8];
      const float4 a1 = *(const float4*)&Qg[r * FDIM + f8 + 4];
      *(short8*)&QL[r][f8] = cvt8(a0, a1);
      const float4 b0 = *(const float4*)&Kg[r * FDIM + f8];
      const float4 b1 = *(const float4*)&Kg[r * FDIM + f8 + 4];
      *(short8*)&KL[r][f8] = cvt8(b0, b1);
    }
  }
  // fused exclusive prefix of chunk states (replaces the old k_scan kernel):
  // 5 tiles of 8 elements/thread; inner chunk-loop issues 8 independent
  // loads per step (ILP-8) -> latency hidden, no serial-chain trap.
  {
    const float* Sg = &S[(size_t)(bh * NC) * SEP * FDIM];
    for (int i0 = tid; i0 < SEP * FDIM; i0 += 256 * 8) {
      float s[8] = {};
      for (int cc = 0; cc < c; ++cc) {
        const float* p = Sg + (size_t)cc * SEP * FDIM + i0;
#pragma unroll
        for (int u = 0; u < 8; ++u) s[u] += p[u * 256];
      }
#pragma unroll
      for (int u = 0; u < 8; ++u) {
        const int i = i0 + u * 256;
        PT[i >> 7][i & 127] = (short)f2bf(s[u]);
      }
    }
  }
  {
    const float* Vg = &Vx[((size_t)bh * LSEQ + t0) * HD];
    for (int i = tid; i < CHUNK * (HD / 4); i += 256) {
      const int t = i >> 4, e4 = (i & 15) << 2;
      const float4 v4 = *(const float4*)&Vg[t * HD + e4];
      VT[e4 + 0][t] = (short)f2bf(v4.x);
      VT[e4 + 1][t] = (short)f2bf(v4.y);
      VT[e4 + 2][t] = (short)f2bf(v4.z);
      VT[e4 + 3][t] = (short)f2bf(v4.w);
    }
    if (tid < CHUNK) VT[64][tid] = (short)0x3F80;   // bf16 1.0
  }
  __syncthreads();

  short8 aQ[4];
#pragma unroll
  for (int ks = 0; ks < 4; ++ks)
    aQ[ks] = *(const short8*)&QL[(wave << 4) + lm][(quad << 3) + (ks << 5)];

  // phase 1: scores
  floatx4 accS[4] = {};
#pragma unroll
  for (int nt = 0; nt < 4; ++nt)
#pragma unroll
    for (int ks = 0; ks < 4; ++ks) {
      const short8 b = *(const short8*)&KL[(nt << 4) + lm][(quad << 3) + (ks << 5)];
      accS[nt] = __builtin_amdgcn_mfma_f32_16x16x32_bf16(aQ[ks], b, accS[nt], 0, 0, 0);
    }
#pragma unroll
  for (int nt = 0; nt < 4; ++nt)
#pragma unroll
    for (int rg = 0; rg < 4; ++rg) {
      const int m = (wave << 4) + (quad << 2) + rg;
      const int t = (nt << 4) + lm;
      ScL[m][t] = (short)((t <= m) ? f2bf(accS[nt][rg]) : 0);
    }

  // phase 2: num = Q @ P (+den col)
  floatx4 accN[5] = {};
#pragma unroll
  for (int nt = 0; nt < 5; ++nt)
#pragma unroll
    for (int ks = 0; ks < 4; ++ks) {
      const short8 b = *(const short8*)&PT[(nt << 4) + lm][(quad << 3) + (ks << 5)];
      accN[nt] = __builtin_amdgcn_mfma_f32_16x16x32_bf16(aQ[ks], b, accN[nt], 0, 0, 0);
    }

  // phase 3: PV = Sc @ Vext (+rowsum col); same-wave ScL access, no barrier
  short8 aS[2];
#pragma unroll
  for (int ks = 0; ks < 2; ++ks)
    aS[ks] = *(const short8*)&ScL[(wave << 4) + lm][(quad << 3) + (ks << 5)];
  floatx4 accV[5] = {};
#pragma unroll
  for (int nt = 0; nt < 5; ++nt)
#pragma unroll
    for (int ks = 0; ks < 2; ++ks) {
      const short8 b = *(const short8*)&VT[(nt << 4) + lm][(quad << 3) + (ks << 5)];
      accV[nt] = __builtin_amdgcn_mfma_f32_16x16x32_bf16(aS[ks], b, accV[nt], 0, 0, 0);
    }

  if (lm == 0) {
#pragma unroll
    for (int rg = 0; rg < 4; ++rg)
      DenL[(wave << 4) + (quad << 2) + rg] = accN[4][rg] + accV[4][rg];
  }

#pragma unroll
  for (int rg = 0; rg < 4; ++rg) {
    const int m = (wave << 4) + (quad << 2) + rg;
    const float rden = 1.0f / DenL[m];
    const int l = t0 + m;
#pragma unroll
    for (int nt = 0; nt < 4; ++nt) {
      const float val = (accN[nt][rg] + accV[nt][rg]) * rden;
      Out[((size_t)(n * LSEQ + l)) * DD + h * HD + (nt << 4) + lm] = val;
    }
  }
}

// ---------------------------------------------------------------------------
extern "C" void kernel_launch(void* const* d_in, const int* in_sizes, int n_in,
                              void* d_out, int out_size, void* d_ws, size_t ws_size,
                              hipStream_t stream) {
  (void)in_sizes; (void)n_in; (void)out_size; (void)ws_size;
  const float* query  = (const float*)d_in[0];
  const float* keyseq = (const float*)d_in[1];
  const float* Wq     = (const float*)d_in[2];
  const float* Wk     = (const float*)d_in[3];
  const float* Wv     = (const float*)d_in[4];
  const float* pc     = (const float*)d_in[5];  // position_coeffs (H,d)
  const float* pw     = (const float*)d_in[6];  // position_weight (H,d,1)
  const float* pb     = (const float*)d_in[7];  // position_bias (H,d)
  float* out = (float*)d_out;

  float* ws = (float*)d_ws;
  float* Qf = ws;                                   // 16*1024*128 f = 8 MB
  float* Kf = Qf + (size_t)NBH * LSEQ * FDIM;       // 8 MB
  float* Vx = Kf + (size_t)NBH * LSEQ * FDIM;       // 4 MB
  float* S  = Vx + (size_t)NBH * LSEQ * HD;         // 16*16*80*128 f = 10.5 MB
  // total ws: ~30.5 MB

  k_proj      <<<768,          256, 0, stream>>>(query, keyseq, Wq, Wk, Wv, pw, pb, pc, Qf, Kf, Vx);
  k_chunk_sums<<<NBH * NC * 2, 256, 0, stream>>>(Kf, Vx, S);
  k_chunk_out <<<NBH * NC,     256, 0, stream>>>(Qf, Kf, Vx, S, out);
}

// Round 10
// 115.696 us; speedup vs baseline: 1.1366x; 1.1226x over previous
//
#include <hip/hip_runtime.h>
#include <cmath>

// Problem constants (from reference): N=2, Lq=1024, Lk=1024, H=8, d=64, P=1, D=512
#define NB    2
#define LSEQ  1024
#define NH    8
#define HD    64
#define DD    512    // NH*HD
#define FDIM  128    // 2*HD  (cos|sin features)
#define EV    65     // HD + 1 (values + denominator unit column)
#define SEP   80     // padded e-extent of the stored chunk state
#define CHUNK 64
#define NC    16     // LSEQ / CHUNK
#define NBH   16     // NB*NH

typedef short short8 __attribute__((ext_vector_type(8)));   // 8 bf16 (4 VGPRs)
typedef float floatx4 __attribute__((ext_vector_type(4)));  // MFMA C/D frag
typedef unsigned short ushort;

__device__ __forceinline__ float softplusf(float x) {
  return fmaxf(x, 0.0f) + log1pf(expf(-fabsf(x)));
}

__device__ __forceinline__ ushort f2bf(float f) {
  unsigned u = __float_as_uint(f);
  u += 0x7fffu + ((u >> 16) & 1u);
  return (ushort)(u >> 16);
}

__device__ __forceinline__ short8 cvt8(float4 a, float4 b) {
  short8 r;
  r[0] = (short)f2bf(a.x); r[1] = (short)f2bf(a.y);
  r[2] = (short)f2bf(a.z); r[3] = (short)f2bf(a.w);
  r[4] = (short)f2bf(b.x); r[5] = (short)f2bf(b.y);
  r[6] = (short)f2bf(b.z); r[7] = (short)f2bf(b.w);
  return r;
}

// ---------------------------------------------------------------------------
// K1: ALL projections, bf16 MFMA, K-slice 64, register double-buffering.
// (identical to the known-best 119.4 µs config)
// ---------------------------------------------------------------------------
__global__ __launch_bounds__(256) void k_proj(
    const float* __restrict__ Xq, const float* __restrict__ Xkv,
    const float* __restrict__ Wq, const float* __restrict__ Wk,
    const float* __restrict__ Wv, const float* __restrict__ pw,
    const float* __restrict__ pb, const float* __restrict__ pc,
    float* __restrict__ Qf, float* __restrict__ Kf, float* __restrict__ Vx)
{
  __shared__ short Al[64][72];   // [m][k] bf16 (9216 B)
  __shared__ short Bl[64][72];   // [e][k] bf16 (9216 B)
  const int b = blockIdx.x;
  int m0, e0, pmode;             // 0 = q, 1 = k, 2 = v
  const float *X, *W;
  if (b < 256) {
    m0 = (b >> 3) << 6; e0 = (b & 7) << 6;
    X = Xq; W = Wq + (size_t)e0 * DD; pmode = 0;
  } else {
    const int bb = b - 256;
    m0 = (bb >> 4) << 6;
    const int nt = bb & 15;
    e0 = (nt & 7) << 6;
    X = Xkv;
    if (nt < 8) { W = Wk + (size_t)e0 * DD; pmode = 1; }
    else        { W = Wv + (size_t)e0 * DD; pmode = 2; }
  }
  const int tid  = threadIdx.x;
  const int r    = tid >> 2;               // staging row 0..63
  const int ko   = (tid & 3) << 4;         // 0,16,32,48 shorts
  const int wave = tid >> 6, lane = tid & 63;
  const int quad = lane >> 4, lm = lane & 15;
  const float* Ag = X + (size_t)(m0 + r) * DD + ko;
  const float* Bg = W + (size_t)r * DD + ko;
  float4 a[4], bb4[4];
#pragma unroll
  for (int u = 0; u < 4; ++u) {
    a[u]   = *(const float4*)(Ag + (u << 2));
    bb4[u] = *(const float4*)(Bg + (u << 2));
  }
  floatx4 acc[4] = {};
  for (int k0 = 0; k0 < DD; k0 += 64) {
    __syncthreads();
    *(short8*)&Al[r][ko]     = cvt8(a[0], a[1]);
    *(short8*)&Al[r][ko + 8] = cvt8(a[2], a[3]);
    *(short8*)&Bl[r][ko]     = cvt8(bb4[0], bb4[1]);
    *(short8*)&Bl[r][ko + 8] = cvt8(bb4[2], bb4[3]);
    __syncthreads();
    if (k0 + 64 < DD) {
#pragma unroll
      for (int u = 0; u < 4; ++u) {
        a[u]   = *(const float4*)(Ag + k0 + 64 + (u << 2));
        bb4[u] = *(const float4*)(Bg + k0 + 64 + (u << 2));
      }
    }
#pragma unroll
    for (int ks = 0; ks < 2; ++ks) {
      const short8 af = *(const short8*)&Al[(wave << 4) + lm][(quad << 3) + (ks << 5)];
#pragma unroll
      for (int t = 0; t < 4; ++t) {
        const short8 bf = *(const short8*)&Bl[(t << 4) + lm][(quad << 3) + (ks << 5)];
        acc[t] = __builtin_amdgcn_mfma_f32_16x16x32_bf16(af, bf, acc[t], 0, 0, 0);
      }
    }
  }
#pragma unroll
  for (int t = 0; t < 4; ++t) {
    const int e = e0 + (t << 4) + lm;
    const int h = e >> 6, jj = e & 63;
    if (pmode == 2) {
#pragma unroll
      for (int rg = 0; rg < 4; ++rg) {
        const int m = m0 + (wave << 4) + (quad << 2) + rg;
        const int n = m >> 10, l = m & 1023;
        Vx[((size_t)(n * NH + h) * LSEQ + l) * HD + jj] = acc[t][rg];
      }
    } else {
      const float pwv = pw[e];
      const float pbv = (pmode == 0) ? pb[e] : 0.0f;
      const float pcv = (pmode == 0) ? pc[e] : 1.0f;
      float* base = (pmode == 0) ? Qf : Kf;
#pragma unroll
      for (int rg = 0; rg < 4; ++rg) {
        const int m = m0 + (wave << 4) + (quad << 2) + rg;
        const int n = m >> 10, l = m & 1023;
        const float v = softplusf(acc[t][rg]) * pcv;
        const float ang = fmaf((float)l, pwv, pbv);
        const float sn = __sinf(ang), cs = __cosf(ang);
        float* dst = &base[((size_t)(n * NH + h) * LSEQ + l) * FDIM + jj];
        dst[0]  = v * cs;
        dst[64] = v * sn;
      }
    }
  }
}

// ---------------------------------------------------------------------------
// K2: per-chunk state sums on bf16 MFMA, stored TRANSPOSED + padded:
// S^T[bh*NC+c][e=0..79][f=0..127] fp32 (flat pow-2 strides; e rows 65..79
// never written). Grid 512: blk = bh*32 + c*2 + fh (fh = f-half of 64 rows).
// ---------------------------------------------------------------------------
__global__ __launch_bounds__(256) void k_chunk_sums(
    const float* __restrict__ Kf, const float* __restrict__ Vx,
    float* __restrict__ S)
{
  const int blk = blockIdx.x;
  const int bh  = blk >> 5;
  const int c   = (blk >> 1) & (NC - 1);
  const int fh  = blk & 1;
  const int f0  = fh << 6;
  const int t0  = c * CHUNK;
  const int tid  = threadIdx.x;
  const int wave = tid >> 6, lane = tid & 63;
  const int quad = lane >> 4, lm = lane & 15;

  __shared__ short KT[64][72];   // [f-f0][t] bf16  9216 B
  __shared__ short VT[80][72];   // [e][t]    bf16 11520 B

  for (int i = tid; i < 64 * 16; i += 256) {
    const int t = i & 63, f4 = (i >> 6) << 2;
    const float4 k4 = *(const float4*)&Kf[((size_t)bh * LSEQ + t0 + t) * FDIM + f0 + f4];
    KT[f4 + 0][t] = (short)f2bf(k4.x);
    KT[f4 + 1][t] = (short)f2bf(k4.y);
    KT[f4 + 2][t] = (short)f2bf(k4.z);
    KT[f4 + 3][t] = (short)f2bf(k4.w);
  }
  for (int i = tid; i < 64 * 16; i += 256) {
    const int t = i & 63, e4 = (i >> 6) << 2;
    const float4 v4 = *(const float4*)&Vx[((size_t)bh * LSEQ + t0 + t) * HD + e4];
    VT[e4 + 0][t] = (short)f2bf(v4.x);
    VT[e4 + 1][t] = (short)f2bf(v4.y);
    VT[e4 + 2][t] = (short)f2bf(v4.z);
    VT[e4 + 3][t] = (short)f2bf(v4.w);
  }
  if (tid < CHUNK) VT[64][tid] = (short)0x3F80;   // bf16 1.0
  __syncthreads();

  short8 aK[2];
#pragma unroll
  for (int ks = 0; ks < 2; ++ks)
    aK[ks] = *(const short8*)&KT[(wave << 4) + lm][(quad << 3) + (ks << 5)];
  floatx4 acc[5] = {};
#pragma unroll
  for (int nt = 0; nt < 5; ++nt)
#pragma unroll
    for (int ks = 0; ks < 2; ++ks) {
      const short8 bf = *(const short8*)&VT[(nt << 4) + lm][(quad << 3) + (ks << 5)];
      acc[nt] = __builtin_amdgcn_mfma_f32_16x16x32_bf16(aK[ks], bf, acc[nt], 0, 0, 0);
    }

  // transposed store: S^T[e][f]
  float* Sb = &S[(size_t)(bh * NC + c) * SEP * FDIM];
#pragma unroll
  for (int nt = 0; nt < 4; ++nt)
#pragma unroll
    for (int rg = 0; rg < 4; ++rg) {
      const int f = f0 + (wave << 4) + (quad << 2) + rg;
      Sb[((nt << 4) + lm) * FDIM + f] = acc[nt][rg];
    }
  if (lm == 0) {
#pragma unroll
    for (int rg = 0; rg < 4; ++rg) {
      const int f = f0 + (wave << 4) + (quad << 2) + rg;
      Sb[64 * FDIM + f] = acc[4][rg];
    }
  }
}

// ---------------------------------------------------------------------------
// K3: exclusive prefix scan over the NC chunk states per bh. Thread owns
// (e,f) elements: 16 INDEPENDENT stride-40KB loads (ILP-16), fp32 accumulate
// in chunk order (same numerics as before), emits bf16 PTb[c][e][f]
// (coalesced 4B reads in f, coalesced 2B writes). Grid NBH*13.
// ---------------------------------------------------------------------------
__global__ __launch_bounds__(256) void k_scan(
    const float* __restrict__ S, ushort* __restrict__ PTb)
{
  const int bh = blockIdx.x / 13;
  const int eg = blockIdx.x % 13;          // 13 groups of 5 e-rows (65 total)
  const size_t cs = (size_t)SEP * FDIM;    // chunk stride (elements)
  const float* Sg = S + (size_t)bh * NC * cs;
  ushort* Pg = PTb + (size_t)bh * NC * cs;
  for (int i = threadIdx.x; i < 5 * FDIM; i += 256) {
    const int e = eg * 5 + (i >> 7);
    const int f = i & 127;
    const int off = e * FDIM + f;
    float v[NC];
#pragma unroll
    for (int c = 0; c < NC; ++c) v[c] = Sg[(size_t)c * cs + off];
    float s = 0.0f;
#pragma unroll
    for (int c = 0; c < NC; ++c) {
      Pg[(size_t)c * cs + off] = f2bf(s);
      s += v[c];
    }
  }
}

// ---------------------------------------------------------------------------
// K4: per-chunk output, all three matmuls on bf16 MFMA (fp32 accumulate).
// PT staging is now a plain coalesced short8 global->LDS copy (prefix is
// pre-converted bf16 in B-frag [e][f] layout by k_scan).
// ---------------------------------------------------------------------------
__global__ __launch_bounds__(256) void k_chunk_out(
    const float* __restrict__ Qf, const float* __restrict__ Kf,
    const float* __restrict__ Vx, const ushort* __restrict__ PTb,
    float* __restrict__ Out)
{
  const int c  = blockIdx.x & (NC - 1);
  const int bh = blockIdx.x >> 4;
  const int n  = bh >> 3, h = bh & 7;
  const int t0 = c * CHUNK;
  const int tid  = threadIdx.x;
  const int wave = tid >> 6, lane = tid & 63;
  const int quad = lane >> 4, lm = lane & 15;

  __shared__ short QL[64][128];    // [t][f] bf16  16384 B
  __shared__ short KL[64][128];    // [t][f] bf16  16384 B
  __shared__ short ScL[64][72];    // [m][t] bf16   9216 B
  __shared__ short PT[80][136];    // [e][f] bf16  21760 B
  __shared__ short VT[80][72];     // [e][t] bf16  11520 B
  __shared__ float DenL[64];       //                256 B

  const float* Qg = &Qf[((size_t)bh * LSEQ + t0) * FDIM];
  const float* Kg = &Kf[((size_t)bh * LSEQ + t0) * FDIM];
  {
    const int f8 = (tid & 15) << 3;
#pragma unroll
    for (int rr = 0; rr < 64; rr += 16) {
      const int r = rr + (tid >> 4);
      const float4 a0 = *(const float4*)&Qg[r * FDIM + f8];
      const float4 a1 = *(const float4*)&Qg[r * FDIM + f8 + 4];
      *(short8*)&QL[r][f8] = cvt8(a0, a1);
      const float4 b0 = *(const float4*)&Kg[r * FDIM + f8];
      const float4 b1 = *(const float4*)&Kg[r * FDIM + f8 + 4];
      *(short8*)&KL[r][f8] = cvt8(b0, b1);
    }
  }
  // PT staging: coalesced 16B copies, no conversion (rows 65..79 stale: only
  // feed discarded D columns of the 5th n-tile)
  {
    const ushort* Pg = &PTb[(size_t)(bh * NC + c) * SEP * FDIM];
    for (int i = tid; i < 65 * 16; i += 256) {
      const int e = i >> 4, f8 = (i & 15) << 3;
      *(short8*)&PT[e][f8] = *(const short8*)&Pg[e * FDIM + f8];
    }
  }
  {
    const float* Vg = &Vx[((size_t)bh * LSEQ + t0) * HD];
    for (int i = tid; i < CHUNK * (HD / 4); i += 256) {
      const int t = i >> 4, e4 = (i & 15) << 2;
      const float4 v4 = *(const float4*)&Vg[t * HD + e4];
      VT[e4 + 0][t] = (short)f2bf(v4.x);
      VT[e4 + 1][t] = (short)f2bf(v4.y);
      VT[e4 + 2][t] = (short)f2bf(v4.z);
      VT[e4 + 3][t] = (short)f2bf(v4.w);
    }
    if (tid < CHUNK) VT[64][tid] = (short)0x3F80;   // bf16 1.0
  }
  __syncthreads();

  short8 aQ[4];
#pragma unroll
  for (int ks = 0; ks < 4; ++ks)
    aQ[ks] = *(const short8*)&QL[(wave << 4) + lm][(quad << 3) + (ks << 5)];

  // phase 1: scores
  floatx4 accS[4] = {};
#pragma unroll
  for (int nt = 0; nt < 4; ++nt)
#pragma unroll
    for (int ks = 0; ks < 4; ++ks) {
      const short8 b = *(const short8*)&KL[(nt << 4) + lm][(quad << 3) + (ks << 5)];
      accS[nt] = __builtin_amdgcn_mfma_f32_16x16x32_bf16(aQ[ks], b, accS[nt], 0, 0, 0);
    }
#pragma unroll
  for (int nt = 0; nt < 4; ++nt)
#pragma unroll
    for (int rg = 0; rg < 4; ++rg) {
      const int m = (wave << 4) + (quad << 2) + rg;
      const int t = (nt << 4) + lm;
      ScL[m][t] = (short)((t <= m) ? f2bf(accS[nt][rg]) : 0);
    }

  // phase 2: num = Q @ P (+den col at e=64)
  floatx4 accN[5] = {};
#pragma unroll
  for (int nt = 0; nt < 5; ++nt)
#pragma unroll
    for (int ks = 0; ks < 4; ++ks) {
      const short8 b = *(const short8*)&PT[(nt << 4) + lm][(quad << 3) + (ks << 5)];
      accN[nt] = __builtin_amdgcn_mfma_f32_16x16x32_bf16(aQ[ks], b, accN[nt], 0, 0, 0);
    }

  // phase 3: PV = Sc @ Vext (+rowsum col); same-wave ScL access, no barrier
  short8 aS[2];
#pragma unroll
  for (int ks = 0; ks < 2; ++ks)
    aS[ks] = *(const short8*)&ScL[(wave << 4) + lm][(quad << 3) + (ks << 5)];
  floatx4 accV[5] = {};
#pragma unroll
  for (int nt = 0; nt < 5; ++nt)
#pragma unroll
    for (int ks = 0; ks < 2; ++ks) {
      const short8 b = *(const short8*)&VT[(nt << 4) + lm][(quad << 3) + (ks << 5)];
      accV[nt] = __builtin_amdgcn_mfma_f32_16x16x32_bf16(aS[ks], b, accV[nt], 0, 0, 0);
    }

  if (lm == 0) {
#pragma unroll
    for (int rg = 0; rg < 4; ++rg)
      DenL[(wave << 4) + (quad << 2) + rg] = accN[4][rg] + accV[4][rg];
  }

#pragma unroll
  for (int rg = 0; rg < 4; ++rg) {
    const int m = (wave << 4) + (quad << 2) + rg;
    const float rden = 1.0f / DenL[m];
    const int l = t0 + m;
#pragma unroll
    for (int nt = 0; nt < 4; ++nt) {
      const float val = (accN[nt][rg] + accV[nt][rg]) * rden;
      Out[((size_t)(n * LSEQ + l)) * DD + h * HD + (nt << 4) + lm] = val;
    }
  }
}

// ---------------------------------------------------------------------------
extern "C" void kernel_launch(void* const* d_in, const int* in_sizes, int n_in,
                              void* d_out, int out_size, void* d_ws, size_t ws_size,
                              hipStream_t stream) {
  (void)in_sizes; (void)n_in; (void)out_size; (void)ws_size;
  const float* query  = (const float*)d_in[0];
  const float* keyseq = (const float*)d_in[1];
  const float* Wq     = (const float*)d_in[2];
  const float* Wk     = (const float*)d_in[3];
  const float* Wv     = (const float*)d_in[4];
  const float* pc     = (const float*)d_in[5];  // position_coeffs (H,d)
  const float* pw     = (const float*)d_in[6];  // position_weight (H,d,1)
  const float* pb     = (const float*)d_in[7];  // position_bias (H,d)
  float* out = (float*)d_out;

  float* ws = (float*)d_ws;
  float*  Qf  = ws;                                   // 16*1024*128 f = 8 MB
  float*  Kf  = Qf + (size_t)NBH * LSEQ * FDIM;       // 8 MB
  float*  Vx  = Kf + (size_t)NBH * LSEQ * FDIM;       // 4 MB
  float*  S   = Vx + (size_t)NBH * LSEQ * HD;         // 16*16*80*128 f = 10.5 MB
  ushort* PTb = (ushort*)(S + (size_t)NBH * NC * SEP * FDIM); // bf16, 5.2 MB

  k_proj      <<<768,          256, 0, stream>>>(query, keyseq, Wq, Wk, Wv, pw, pb, pc, Qf, Kf, Vx);
  k_chunk_sums<<<NBH * NC * 2, 256, 0, stream>>>(Kf, Vx, S);
  k_scan      <<<NBH * 13,     256, 0, stream>>>(S, PTb);
  k_chunk_out <<<NBH * NC,     256, 0, stream>>>(Qf, Kf, Vx, PTb, out);
}

// Round 11
// 112.592 us; speedup vs baseline: 1.1679x; 1.0276x over previous
//
#include <hip/hip_runtime.h>
#include <cmath>

// Problem constants (from reference): N=2, Lq=1024, Lk=1024, H=8, d=64, P=1, D=512
#define NB    2
#define LSEQ  1024
#define NH    8
#define HD    64
#define DD    512    // NH*HD
#define FDIM  128    // 2*HD  (cos|sin features)
#define EV    65     // HD + 1 (values + denominator unit column)
#define SEP   80     // padded e-extent of the stored chunk state
#define CHUNK 64
#define NC    16     // LSEQ / CHUNK
#define NBH   16     // NB*NH

typedef short short8 __attribute__((ext_vector_type(8)));   // 8 bf16 (4 VGPRs)
typedef float floatx4 __attribute__((ext_vector_type(4)));  // MFMA C/D frag
typedef unsigned short ushort;

__device__ __forceinline__ float softplusf(float x) {
  return fmaxf(x, 0.0f) + log1pf(expf(-fabsf(x)));
}

__device__ __forceinline__ ushort f2bf(float f) {
  unsigned u = __float_as_uint(f);
  u += 0x7fffu + ((u >> 16) & 1u);
  return (ushort)(u >> 16);
}

__device__ __forceinline__ short8 cvt8(float4 a, float4 b) {
  short8 r;
  r[0] = (short)f2bf(a.x); r[1] = (short)f2bf(a.y);
  r[2] = (short)f2bf(a.z); r[3] = (short)f2bf(a.w);
  r[4] = (short)f2bf(b.x); r[5] = (short)f2bf(b.y);
  r[6] = (short)f2bf(b.z); r[7] = (short)f2bf(b.w);
  return r;
}

// ---------------------------------------------------------------------------
// K1: ALL projections, bf16 MFMA, K-slice 64, register double-buffering.
// Outputs now stored bf16 (values identical to the old fp32->consumer-side
// rounding — the rounding just moved to the producer). Row layouts unchanged.
// ---------------------------------------------------------------------------
__global__ __launch_bounds__(256) void k_proj(
    const float* __restrict__ Xq, const float* __restrict__ Xkv,
    const float* __restrict__ Wq, const float* __restrict__ Wk,
    const float* __restrict__ Wv, const float* __restrict__ pw,
    const float* __restrict__ pb, const float* __restrict__ pc,
    ushort* __restrict__ Qfb, ushort* __restrict__ Kfb,
    ushort* __restrict__ Vxb)
{
  __shared__ short Al[64][72];   // [m][k] bf16 (9216 B)
  __shared__ short Bl[64][72];   // [e][k] bf16 (9216 B)
  const int b = blockIdx.x;
  int m0, e0, pmode;             // 0 = q, 1 = k, 2 = v
  const float *X, *W;
  if (b < 256) {
    m0 = (b >> 3) << 6; e0 = (b & 7) << 6;
    X = Xq; W = Wq + (size_t)e0 * DD; pmode = 0;
  } else {
    const int bb = b - 256;
    m0 = (bb >> 4) << 6;
    const int nt = bb & 15;
    e0 = (nt & 7) << 6;
    X = Xkv;
    if (nt < 8) { W = Wk + (size_t)e0 * DD; pmode = 1; }
    else        { W = Wv + (size_t)e0 * DD; pmode = 2; }
  }
  const int tid  = threadIdx.x;
  const int r    = tid >> 2;               // staging row 0..63
  const int ko   = (tid & 3) << 4;         // 0,16,32,48 shorts
  const int wave = tid >> 6, lane = tid & 63;
  const int quad = lane >> 4, lm = lane & 15;
  const float* Ag = X + (size_t)(m0 + r) * DD + ko;
  const float* Bg = W + (size_t)r * DD + ko;
  float4 a[4], bb4[4];
#pragma unroll
  for (int u = 0; u < 4; ++u) {
    a[u]   = *(const float4*)(Ag + (u << 2));
    bb4[u] = *(const float4*)(Bg + (u << 2));
  }
  floatx4 acc[4] = {};
  for (int k0 = 0; k0 < DD; k0 += 64) {
    __syncthreads();
    *(short8*)&Al[r][ko]     = cvt8(a[0], a[1]);
    *(short8*)&Al[r][ko + 8] = cvt8(a[2], a[3]);
    *(short8*)&Bl[r][ko]     = cvt8(bb4[0], bb4[1]);
    *(short8*)&Bl[r][ko + 8] = cvt8(bb4[2], bb4[3]);
    __syncthreads();
    if (k0 + 64 < DD) {
#pragma unroll
      for (int u = 0; u < 4; ++u) {
        a[u]   = *(const float4*)(Ag + k0 + 64 + (u << 2));
        bb4[u] = *(const float4*)(Bg + k0 + 64 + (u << 2));
      }
    }
#pragma unroll
    for (int ks = 0; ks < 2; ++ks) {
      const short8 af = *(const short8*)&Al[(wave << 4) + lm][(quad << 3) + (ks << 5)];
#pragma unroll
      for (int t = 0; t < 4; ++t) {
        const short8 bf = *(const short8*)&Bl[(t << 4) + lm][(quad << 3) + (ks << 5)];
        acc[t] = __builtin_amdgcn_mfma_f32_16x16x32_bf16(af, bf, acc[t], 0, 0, 0);
      }
    }
  }
#pragma unroll
  for (int t = 0; t < 4; ++t) {
    const int e = e0 + (t << 4) + lm;
    const int h = e >> 6, jj = e & 63;
    if (pmode == 2) {
#pragma unroll
      for (int rg = 0; rg < 4; ++rg) {
        const int m = m0 + (wave << 4) + (quad << 2) + rg;
        const int n = m >> 10, l = m & 1023;
        Vxb[((size_t)(n * NH + h) * LSEQ + l) * HD + jj] = f2bf(acc[t][rg]);
      }
    } else {
      const float pwv = pw[e];
      const float pbv = (pmode == 0) ? pb[e] : 0.0f;
      const float pcv = (pmode == 0) ? pc[e] : 1.0f;
      ushort* base = (pmode == 0) ? Qfb : Kfb;
#pragma unroll
      for (int rg = 0; rg < 4; ++rg) {
        const int m = m0 + (wave << 4) + (quad << 2) + rg;
        const int n = m >> 10, l = m & 1023;
        const float v = softplusf(acc[t][rg]) * pcv;
        const float ang = fmaf((float)l, pwv, pbv);
        ushort* dst = &base[((size_t)(n * NH + h) * LSEQ + l) * FDIM + jj];
        dst[0]  = f2bf(v * __cosf(ang));
        dst[64] = f2bf(v * __sinf(ang));
      }
    }
  }
}

// ---------------------------------------------------------------------------
// K2: per-chunk state sums on bf16 MFMA, stored TRANSPOSED + padded fp32:
// S^T[bh*NC+c][e=0..79][f=0..127]. Inputs now bf16 -> staging is short8
// reads + 2B LDS transpose writes (2-way max aliasing = free).
// Grid 512: blk = bh*32 + c*2 + fh (fh = f-half of 64 rows).
// ---------------------------------------------------------------------------
__global__ __launch_bounds__(256) void k_chunk_sums(
    const ushort* __restrict__ Kfb, const ushort* __restrict__ Vxb,
    float* __restrict__ S)
{
  const int blk = blockIdx.x;
  const int bh  = blk >> 5;
  const int c   = (blk >> 1) & (NC - 1);
  const int fh  = blk & 1;
  const int f0  = fh << 6;
  const int t0  = c * CHUNK;
  const int tid  = threadIdx.x;
  const int wave = tid >> 6, lane = tid & 63;
  const int quad = lane >> 4, lm = lane & 15;

  __shared__ short KT[64][72];   // [f-f0][t] bf16  9216 B
  __shared__ short VT[80][72];   // [e][t]    bf16 11520 B

  for (int i = tid; i < 64 * 8; i += 256) {
    const int t = i & 63, f8 = (i >> 6) << 3;
    const short8 k8 = *(const short8*)&Kfb[((size_t)bh * LSEQ + t0 + t) * FDIM + f0 + f8];
#pragma unroll
    for (int u = 0; u < 8; ++u) KT[f8 + u][t] = k8[u];
  }
  for (int i = tid; i < 64 * 8; i += 256) {
    const int t = i & 63, e8 = (i >> 6) << 3;
    const short8 v8 = *(const short8*)&Vxb[((size_t)bh * LSEQ + t0 + t) * HD + e8];
#pragma unroll
    for (int u = 0; u < 8; ++u) VT[e8 + u][t] = v8[u];
  }
  if (tid < CHUNK) VT[64][tid] = (short)0x3F80;   // bf16 1.0
  __syncthreads();

  short8 aK[2];
#pragma unroll
  for (int ks = 0; ks < 2; ++ks)
    aK[ks] = *(const short8*)&KT[(wave << 4) + lm][(quad << 3) + (ks << 5)];
  floatx4 acc[5] = {};
#pragma unroll
  for (int nt = 0; nt < 5; ++nt)
#pragma unroll
    for (int ks = 0; ks < 2; ++ks) {
      const short8 bf = *(const short8*)&VT[(nt << 4) + lm][(quad << 3) + (ks << 5)];
      acc[nt] = __builtin_amdgcn_mfma_f32_16x16x32_bf16(aK[ks], bf, acc[nt], 0, 0, 0);
    }

  // transposed store: S^T[e][f]
  float* Sb = &S[(size_t)(bh * NC + c) * SEP * FDIM];
#pragma unroll
  for (int nt = 0; nt < 4; ++nt)
#pragma unroll
    for (int rg = 0; rg < 4; ++rg) {
      const int f = f0 + (wave << 4) + (quad << 2) + rg;
      Sb[((nt << 4) + lm) * FDIM + f] = acc[nt][rg];
    }
  if (lm == 0) {
#pragma unroll
    for (int rg = 0; rg < 4; ++rg) {
      const int f = f0 + (wave << 4) + (quad << 2) + rg;
      Sb[64 * FDIM + f] = acc[4][rg];
    }
  }
}

// ---------------------------------------------------------------------------
// K3: exclusive prefix scan over the NC chunk states per bh. Thread owns
// (e,f) elements: 16 INDEPENDENT stride-40KB loads (ILP-16), fp32 accumulate
// in chunk order, emits bf16 PTb[c][e][f] (coalesced reads in f, coalesced
// 2B writes). Grid NBH*13.
// ---------------------------------------------------------------------------
__global__ __launch_bounds__(256) void k_scan(
    const float* __restrict__ S, ushort* __restrict__ PTb)
{
  const int bh = blockIdx.x / 13;
  const int eg = blockIdx.x % 13;          // 13 groups of 5 e-rows (65 total)
  const size_t cs = (size_t)SEP * FDIM;    // chunk stride (elements)
  const float* Sg = S + (size_t)bh * NC * cs;
  ushort* Pg = PTb + (size_t)bh * NC * cs;
  for (int i = threadIdx.x; i < 5 * FDIM; i += 256) {
    const int e = eg * 5 + (i >> 7);
    const int f = i & 127;
    const int off = e * FDIM + f;
    float v[NC];
#pragma unroll
    for (int c = 0; c < NC; ++c) v[c] = Sg[(size_t)c * cs + off];
    float s = 0.0f;
#pragma unroll
    for (int c = 0; c < NC; ++c) {
      Pg[(size_t)c * cs + off] = f2bf(s);
      s += v[c];
    }
  }
}

// ---------------------------------------------------------------------------
// K4: per-chunk output, all three matmuls on bf16 MFMA (fp32 accumulate).
// All staging is now conversion-free: QL/KL/PT are coalesced short8 copies,
// VT is a short8-read + 2B LDS transpose.
// ---------------------------------------------------------------------------
__global__ __launch_bounds__(256) void k_chunk_out(
    const ushort* __restrict__ Qfb, const ushort* __restrict__ Kfb,
    const ushort* __restrict__ Vxb, const ushort* __restrict__ PTb,
    float* __restrict__ Out)
{
  const int c  = blockIdx.x & (NC - 1);
  const int bh = blockIdx.x >> 4;
  const int n  = bh >> 3, h = bh & 7;
  const int t0 = c * CHUNK;
  const int tid  = threadIdx.x;
  const int wave = tid >> 6, lane = tid & 63;
  const int quad = lane >> 4, lm = lane & 15;

  __shared__ short QL[64][128];    // [t][f] bf16  16384 B
  __shared__ short KL[64][128];    // [t][f] bf16  16384 B
  __shared__ short ScL[64][72];    // [m][t] bf16   9216 B
  __shared__ short PT[80][136];    // [e][f] bf16  21760 B
  __shared__ short VT[80][72];     // [e][t] bf16  11520 B
  __shared__ float DenL[64];       //                256 B

  const ushort* Qg = &Qfb[((size_t)bh * LSEQ + t0) * FDIM];
  const ushort* Kg = &Kfb[((size_t)bh * LSEQ + t0) * FDIM];
  for (int i = tid; i < 64 * 16; i += 256) {
    const int r = i >> 4, f8 = (i & 15) << 3;
    *(short8*)&QL[r][f8] = *(const short8*)&Qg[r * FDIM + f8];
    *(short8*)&KL[r][f8] = *(const short8*)&Kg[r * FDIM + f8];
  }
  // PT staging: coalesced 16B copies (rows 65..79 stale: only feed the
  // discarded D columns of the 5th n-tile)
  {
    const ushort* Pg = &PTb[(size_t)(bh * NC + c) * SEP * FDIM];
    for (int i = tid; i < 65 * 16; i += 256) {
      const int e = i >> 4, f8 = (i & 15) << 3;
      *(short8*)&PT[e][f8] = *(const short8*)&Pg[e * FDIM + f8];
    }
  }
  for (int i = tid; i < 64 * 8; i += 256) {
    const int t = i & 63, e8 = (i >> 6) << 3;
    const short8 v8 = *(const short8*)&Vxb[((size_t)bh * LSEQ + t0 + t) * HD + e8];
#pragma unroll
    for (int u = 0; u < 8; ++u) VT[e8 + u][t] = v8[u];
  }
  if (tid < CHUNK) VT[64][tid] = (short)0x3F80;   // bf16 1.0
  __syncthreads();

  short8 aQ[4];
#pragma unroll
  for (int ks = 0; ks < 4; ++ks)
    aQ[ks] = *(const short8*)&QL[(wave << 4) + lm][(quad << 3) + (ks << 5)];

  // phase 1: scores
  floatx4 accS[4] = {};
#pragma unroll
  for (int nt = 0; nt < 4; ++nt)
#pragma unroll
    for (int ks = 0; ks < 4; ++ks) {
      const short8 b = *(const short8*)&KL[(nt << 4) + lm][(quad << 3) + (ks << 5)];
      accS[nt] = __builtin_amdgcn_mfma_f32_16x16x32_bf16(aQ[ks], b, accS[nt], 0, 0, 0);
    }
#pragma unroll
  for (int nt = 0; nt < 4; ++nt)
#pragma unroll
    for (int rg = 0; rg < 4; ++rg) {
      const int m = (wave << 4) + (quad << 2) + rg;
      const int t = (nt << 4) + lm;
      ScL[m][t] = (short)((t <= m) ? f2bf(accS[nt][rg]) : 0);
    }

  // phase 2: num = Q @ P (+den col at e=64)
  floatx4 accN[5] = {};
#pragma unroll
  for (int nt = 0; nt < 5; ++nt)
#pragma unroll
    for (int ks = 0; ks < 4; ++ks) {
      const short8 b = *(const short8*)&PT[(nt << 4) + lm][(quad << 3) + (ks << 5)];
      accN[nt] = __builtin_amdgcn_mfma_f32_16x16x32_bf16(aQ[ks], b, accN[nt], 0, 0, 0);
    }

  // phase 3: PV = Sc @ Vext (+rowsum col); same-wave ScL access, no barrier
  short8 aS[2];
#pragma unroll
  for (int ks = 0; ks < 2; ++ks)
    aS[ks] = *(const short8*)&ScL[(wave << 4) + lm][(quad << 3) + (ks << 5)];
  floatx4 accV[5] = {};
#pragma unroll
  for (int nt = 0; nt < 5; ++nt)
#pragma unroll
    for (int ks = 0; ks < 2; ++ks) {
      const short8 b = *(const short8*)&VT[(nt << 4) + lm][(quad << 3) + (ks << 5)];
      accV[nt] = __builtin_amdgcn_mfma_f32_16x16x32_bf16(aS[ks], b, accV[nt], 0, 0, 0);
    }

  if (lm == 0) {
#pragma unroll
    for (int rg = 0; rg < 4; ++rg)
      DenL[(wave << 4) + (quad << 2) + rg] = accN[4][rg] + accV[4][rg];
  }

#pragma unroll
  for (int rg = 0; rg < 4; ++rg) {
    const int m = (wave << 4) + (quad << 2) + rg;
    const float rden = 1.0f / DenL[m];
    const int l = t0 + m;
#pragma unroll
    for (int nt = 0; nt < 4; ++nt) {
      const float val = (accN[nt][rg] + accV[nt][rg]) * rden;
      Out[((size_t)(n * LSEQ + l)) * DD + h * HD + (nt << 4) + lm] = val;
    }
  }
}

// ---------------------------------------------------------------------------
extern "C" void kernel_launch(void* const* d_in, const int* in_sizes, int n_in,
                              void* d_out, int out_size, void* d_ws, size_t ws_size,
                              hipStream_t stream) {
  (void)in_sizes; (void)n_in; (void)out_size; (void)ws_size;
  const float* query  = (const float*)d_in[0];
  const float* keyseq = (const float*)d_in[1];
  const float* Wq     = (const float*)d_in[2];
  const float* Wk     = (const float*)d_in[3];
  const float* Wv     = (const float*)d_in[4];
  const float* pc     = (const float*)d_in[5];  // position_coeffs (H,d)
  const float* pw     = (const float*)d_in[6];  // position_weight (H,d,1)
  const float* pb     = (const float*)d_in[7];  // position_bias (H,d)
  float* out = (float*)d_out;

  // workspace: bf16 intermediates (row layouts), fp32 chunk states, bf16 prefix
  ushort* Qfb = (ushort*)d_ws;                            // 4 MB
  ushort* Kfb = Qfb + (size_t)NBH * LSEQ * FDIM;          // 4 MB
  ushort* Vxb = Kfb + (size_t)NBH * LSEQ * FDIM;          // 2 MB
  float*  S   = (float*)(Vxb + (size_t)NBH * LSEQ * HD);  // 10.5 MB
  ushort* PTb = (ushort*)(S + (size_t)NBH * NC * SEP * FDIM); // 5.2 MB

  k_proj      <<<768,          256, 0, stream>>>(query, keyseq, Wq, Wk, Wv, pw, pb, pc, Qfb, Kfb, Vxb);
  k_chunk_sums<<<NBH * NC * 2, 256, 0, stream>>>(Kfb, Vxb, S);
  k_scan      <<<NBH * 13,     256, 0, stream>>>(S, PTb);
  k_chunk_out <<<NBH * NC,     256, 0, stream>>>(Qfb, Kfb, Vxb, PTb, out);
}